// Round 2
// baseline (160.996 us; speedup 1.0000x reference)
//
#include <hip/hip_runtime.h>
#include <math.h>

#define NQ 12
#define NSTATE 4096
#define NL 4
#define NC 10
#define NB 512
#define BN_EPS 1e-5f

// One block per batch sample. State vector (4096 complex) lives in LDS as
// separate re/im planes (32 KB). Fused (Rot * RY) single-qubit gates + CNOT ring.
__global__ __launch_bounds__(256) void vqc_kernel(
    const float* __restrict__ x, const float* __restrict__ w,
    const float* __restrict__ bias, float* __restrict__ probs)
{
    __shared__ float re[NSTATE];
    __shared__ float im[NSTATE];
    const int b = blockIdx.x;
    const int t = threadIdx.x;

    for (int i = t; i < NSTATE; i += 256) { re[i] = 0.f; im[i] = 0.f; }
    if (t == 0) re[0] = 1.f;
    __syncthreads();

    for (int l = 0; l < NL; ++l) {
        // ---- fused RY(x) then Rot(w) per wire (gates on distinct wires commute) ----
        for (int q = 0; q < NQ; ++q) {
            const float xq = 0.5f * x[b*NQ + q];
            const float cx = cosf(xq), sx = sinf(xq);
            const int wi = (l*NQ + q)*3;
            const float phi = w[wi], th = w[wi+1], om = w[wi+2];
            const float ct = cosf(0.5f*th), st = sinf(0.5f*th);
            const float a = 0.5f*(phi + om), d = 0.5f*(phi - om);
            const float ca = cosf(a), sa = sinf(a);
            const float cd = cosf(d), sd = sinf(d);
            // Rot = RZ(om) RY(th) RZ(phi):
            // u00 = e^{-ia}ct  u01 = -e^{id}st
            // u10 = e^{-id}st  u11 =  e^{ia}ct
            const float u00r =  ca*ct, u00i = -sa*ct;
            const float u01r = -cd*st, u01i = -sd*st;
            const float u10r =  cd*st, u10i = -sd*st;
            const float u11r =  ca*ct, u11i =  sa*ct;
            // M = Rot * RY(x)  (RY is real [[cx,-sx],[sx,cx]])
            const float m00r = u00r*cx + u01r*sx, m00i = u00i*cx + u01i*sx;
            const float m01r = u01r*cx - u00r*sx, m01i = u01i*cx - u00i*sx;
            const float m10r = u10r*cx + u11r*sx, m10i = u10i*cx + u11i*sx;
            const float m11r = u11r*cx - u10r*sx, m11i = u11i*cx - u10i*sx;

            const int bit = 1 << (11 - q);   // qubit q == bit (11-q), axis-major flatten
            const int lo  = bit - 1;
            #pragma unroll
            for (int p = t; p < NSTATE/2; p += 256) {
                const int i0 = ((p & ~lo) << 1) | (p & lo);
                const int i1 = i0 | bit;
                const float r0 = re[i0], s0 = im[i0];
                const float r1 = re[i1], s1 = im[i1];
                re[i0] = m00r*r0 - m00i*s0 + m01r*r1 - m01i*s1;
                im[i0] = m00r*s0 + m00i*r0 + m01r*s1 + m01i*r1;
                re[i1] = m10r*r0 - m10i*s0 + m11r*r1 - m11i*s1;
                im[i1] = m10r*s0 + m10i*r0 + m11r*s1 + m11i*r1;
            }
            __syncthreads();
        }
        // ---- ring of CNOTs ----
        for (int q = 0; q < NQ; ++q) {
            const int cb = 1 << (11 - q);
            const int tb = 1 << (11 - ((q + 1) % NQ));
            const int b1 = (cb < tb) ? cb : tb;
            const int b2 = (cb < tb) ? tb : cb;
            const int l1 = b1 - 1, l2 = b2 - 1;
            #pragma unroll
            for (int p = t; p < NSTATE/4; p += 256) {
                int i = ((p & ~l1) << 1) | (p & l1);   // insert 0 at lower bit
                i = ((i & ~l2) << 1) | (i & l2);       // insert 0 at upper bit
                i |= cb;                               // control = 1
                const int j = i | tb;                  // target partner
                const float tr = re[i]; re[i] = re[j]; re[j] = tr;
                const float ti = im[i]; im[i] = im[j]; im[j] = ti;
            }
            __syncthreads();
        }
    }

    // ---- readout: <Z_c> for c in 0..9, then softmax(expz + bias) ----
    float acc[NC];
    #pragma unroll
    for (int c = 0; c < NC; ++c) acc[c] = 0.f;
    for (int i = t; i < NSTATE; i += 256) {
        const float p = re[i]*re[i] + im[i]*im[i];
        #pragma unroll
        for (int c = 0; c < NC; ++c)
            acc[c] += (i & (1 << (11 - c))) ? -p : p;
    }
    #pragma unroll
    for (int off = 32; off >= 1; off >>= 1) {
        #pragma unroll
        for (int c = 0; c < NC; ++c)
            acc[c] += __shfl_down(acc[c], off, 64);
    }
    __syncthreads();                       // done reading re/im; reuse re for partials
    const int wave = t >> 6, lane = t & 63;
    if (lane == 0) {
        #pragma unroll
        for (int c = 0; c < NC; ++c) re[wave*NC + c] = acc[c];
    }
    __syncthreads();
    if (t == 0) {
        float ez[NC];
        float mx = -1e30f;
        #pragma unroll
        for (int c = 0; c < NC; ++c) {
            ez[c] = re[c] + re[NC + c] + re[2*NC + c] + re[3*NC + c] + bias[c];
            mx = fmaxf(mx, ez[c]);
        }
        float sum = 0.f;
        #pragma unroll
        for (int c = 0; c < NC; ++c) { ez[c] = expf(ez[c] - mx); sum += ez[c]; }
        const float inv = 1.f / sum;
        #pragma unroll
        for (int c = 0; c < NC; ++c) probs[b*NC + c] = ez[c] * inv;
    }
}

// BatchNorm1d (training mode, biased var) over the batch dim, in place on d_out.
// One block per class; thread t owns rows t and t+256 (no cross-thread overlap).
__global__ __launch_bounds__(256) void bn_kernel(
    float* __restrict__ probs, const float* __restrict__ gamma,
    const float* __restrict__ beta)
{
    const int c = blockIdx.x;
    const int t = threadIdx.x;
    const float v0 = probs[t*NC + c];
    const float v1 = probs[(t + 256)*NC + c];
    float s  = v0 + v1;
    float ss = v0*v0 + v1*v1;
    #pragma unroll
    for (int off = 32; off >= 1; off >>= 1) {
        s  += __shfl_down(s,  off, 64);
        ss += __shfl_down(ss, off, 64);
    }
    __shared__ float sm[8];
    __shared__ float stat[2];
    const int wave = t >> 6, lane = t & 63;
    if (lane == 0) { sm[wave] = s; sm[4 + wave] = ss; }
    __syncthreads();
    if (t == 0) {
        const float S  = sm[0] + sm[1] + sm[2] + sm[3];
        const float SS = sm[4] + sm[5] + sm[6] + sm[7];
        const float mu  = S * (1.f/512.f);
        const float var = SS * (1.f/512.f) - mu*mu;
        stat[0] = mu;
        stat[1] = 1.f / sqrtf(var + BN_EPS);
    }
    __syncthreads();
    const float mu = stat[0], inv = stat[1];
    const float g = gamma[c], bt = beta[c];
    probs[t*NC + c]       = (v0 - mu) * inv * g + bt;
    probs[(t + 256)*NC + c] = (v1 - mu) * inv * g + bt;
}

extern "C" void kernel_launch(void* const* d_in, const int* in_sizes, int n_in,
                              void* d_out, int out_size, void* d_ws, size_t ws_size,
                              hipStream_t stream) {
    const float* x     = (const float*)d_in[0];   // (512, 12)
    const float* w     = (const float*)d_in[1];   // (4, 12, 3)
    const float* bias  = (const float*)d_in[2];   // (10,)
    const float* gamma = (const float*)d_in[3];   // (10,)
    const float* beta  = (const float*)d_in[4];   // (10,)
    float* out = (float*)d_out;                   // (512, 10) float32

    vqc_kernel<<<NB, 256, 0, stream>>>(x, w, bias, out);
    bn_kernel<<<NC, 256, 0, stream>>>(out, gamma, beta);
}

// Round 3
// 97.979 us; speedup vs baseline: 1.6432x; 1.6432x over previous
//
#include <hip/hip_runtime.h>
#include <math.h>

#define NQ 12
#define NL 4
#define NC 10
#define NB 512
#define BN_EPS 1e-5f

// Complex 2x2 butterfly: (A,B) <- M * (A,B), M = [[m0+i m1, m2+i m3],[m4+i m5, m6+i m7]]
__device__ __forceinline__ void bfly(float2& A, float2& B,
    float m0, float m1, float m2, float m3,
    float m4, float m5, float m6, float m7)
{
    const float2 a0 = A, b0 = B;
    A.x = m0*a0.x - m1*a0.y + m2*b0.x - m3*b0.y;
    A.y = m0*a0.y + m1*a0.x + m2*b0.y + m3*b0.x;
    B.x = m4*a0.x - m5*a0.y + m6*b0.x - m7*b0.y;
    B.y = m4*a0.y + m5*a0.x + m6*b0.y + m7*b0.x;
}

// Register-tiled VQC: one block per sample; 16 amps (4 local qubits) per thread.
// Stage s holds qubits 4s..4s+3 local (r-bit 3-g <-> qubit 4s+g).
// LDS slot function: slot(t,r) = (r<<8) | (phi(t) ^ 17*r), phi(t) = t ^ (t>>4).
// Ring-CNOT permutation M (j_p = parity(i>>p), j_11 = parity(i&0x7FF)) is fused
// into the C->A' write addresses and into the readout sign bits.
__global__ __launch_bounds__(256) void vqc_kernel(
    const float* __restrict__ x, const float* __restrict__ w,
    const float* __restrict__ bias, float* __restrict__ probs)
{
    __shared__ float2 buf[4096];                 // 32 KB staging
    __shared__ __align__(16) float gm[48][8];    // 48 fused gate matrices
    __shared__ float red[4*NC];

    const int b = blockIdx.x;
    const int t = threadIdx.x;

    // ---- one-time: all 48 fused (Rot * RY) matrices ----
    if (t < 48) {
        const int l = t / NQ, q = t % NQ;
        const float xq = 0.5f * x[b*NQ + q];
        const float cx = cosf(xq), sx = sinf(xq);
        const int wi = (l*NQ + q)*3;
        const float phi = w[wi], tht = w[wi+1], om = w[wi+2];
        const float ct = cosf(0.5f*tht), st = sinf(0.5f*tht);
        const float aa = 0.5f*(phi + om), dd = 0.5f*(phi - om);
        const float ca = cosf(aa), sa = sinf(aa);
        const float cd = cosf(dd), sd = sinf(dd);
        const float u00r =  ca*ct, u00i = -sa*ct;
        const float u01r = -cd*st, u01i = -sd*st;
        const float u10r =  cd*st, u10i = -sd*st;
        const float u11r =  ca*ct, u11i =  sa*ct;
        gm[t][0] = u00r*cx + u01r*sx;  gm[t][1] = u00i*cx + u01i*sx;
        gm[t][2] = u01r*cx - u00r*sx;  gm[t][3] = u01i*cx - u00i*sx;
        gm[t][4] = u10r*cx + u11r*sx;  gm[t][5] = u10i*cx + u11i*sx;
        gm[t][6] = u11r*cx - u10r*sx;  gm[t][7] = u11i*cx - u10i*sx;
    }
    __syncthreads();

    // ---- registers: stage-A layout, global i = (r<<8)|t ----
    float2 a[16];
    #pragma unroll
    for (int r = 0; r < 16; ++r) a[r] = make_float2(0.f, 0.f);
    if (t == 0) a[0].x = 1.f;

    const int tl = t & 15, th4 = t >> 4;
    const int phit = t ^ th4;                       // phi(t)
    const int vAB = (th4 << 8) | (tl ^ (th4 * 17)); // A->B write base
    const int wBC = (tl << 8) | ((th4 ^ tl) * 17);  // B->C write base

    // ---- C->A' (CNOT ring) per-thread constants ----
    const unsigned b0_ = t & 1u, b1_ = (t>>1)&1u, b2_ = (t>>2)&1u, b3_ = (t>>3)&1u,
                   b4_ = (t>>4)&1u, b5_ = (t>>5)&1u, b6_ = (t>>6)&1u, b7_ = (t>>7)&1u;
    const unsigned P7 = b7_, P6 = P7^b6_, P5 = P6^b5_, P4 = P5^b4_,
                   P3 = P4^b3_, P2 = P3^b2_, P1 = P2^b1_, T = P1^b0_;  // Pk = parity(t>>k)
    // base_j = M(i) for i = (t<<4)|r with r-dependent parts zeroed (par(r)=0, K_r=0)
    const unsigned base_j = ((T ^ b7_) << 11) | (P6 << 10) | (P5 << 9) | (P4 << 8)
                          | (P3 << 7) | (P2 << 6) | (P1 << 5) | (T << 4)
                          | (T ? 0xFu : 0u);
    const unsigned rA = (base_j >> 8) & 15u;
    const unsigned tA = base_j & 255u;
    const unsigned baseCA = (rA << 8) | ((tA ^ (tA >> 4)) ^ (rA * 17u));

    for (int l = 0; l < NL; ++l) {
        // ---- stage 0: qubits 0..3 (register butterflies) ----
        #pragma unroll
        for (int g = 0; g < 4; ++g) {
            const float* mp = gm[l*12 + g];
            const float m0=mp[0],m1=mp[1],m2=mp[2],m3=mp[3],
                        m4=mp[4],m5=mp[5],m6=mp[6],m7=mp[7];
            const int bit = 8 >> g;
            #pragma unroll
            for (int r0 = 0; r0 < 16; ++r0)
                if (!(r0 & bit)) bfly(a[r0], a[r0|bit], m0,m1,m2,m3,m4,m5,m6,m7);
        }
        // ---- transition A->B ----
        __syncthreads();
        #pragma unroll
        for (int r = 0; r < 16; ++r) buf[vAB ^ (r*17)] = a[r];
        __syncthreads();
        #pragma unroll
        for (int r = 0; r < 16; ++r) a[r] = buf[(r<<8) | (phit ^ (r*17))];

        // ---- stage 1: qubits 4..7 ----
        #pragma unroll
        for (int g = 0; g < 4; ++g) {
            const float* mp = gm[l*12 + 4 + g];
            const float m0=mp[0],m1=mp[1],m2=mp[2],m3=mp[3],
                        m4=mp[4],m5=mp[5],m6=mp[6],m7=mp[7];
            const int bit = 8 >> g;
            #pragma unroll
            for (int r0 = 0; r0 < 16; ++r0)
                if (!(r0 & bit)) bfly(a[r0], a[r0|bit], m0,m1,m2,m3,m4,m5,m6,m7);
        }
        // ---- transition B->C ----
        __syncthreads();
        #pragma unroll
        for (int r = 0; r < 16; ++r) buf[wBC ^ r] = a[r];
        __syncthreads();
        #pragma unroll
        for (int r = 0; r < 16; ++r) a[r] = buf[(r<<8) | (phit ^ (r*17))];

        // ---- stage 2: qubits 8..11 ----
        #pragma unroll
        for (int g = 0; g < 4; ++g) {
            const float* mp = gm[l*12 + 8 + g];
            const float m0=mp[0],m1=mp[1],m2=mp[2],m3=mp[3],
                        m4=mp[4],m5=mp[5],m6=mp[6],m7=mp[7];
            const int bit = 8 >> g;
            #pragma unroll
            for (int r0 = 0; r0 < 16; ++r0)
                if (!(r0 & bit)) bfly(a[r0], a[r0|bit], m0,m1,m2,m3,m4,m5,m6,m7);
        }
        if (l < NL-1) {
            // ---- transition C->A' with ring-CNOT permutation fused ----
            __syncthreads();
            #pragma unroll
            for (int r = 0; r < 16; ++r) {
                const unsigned k3 = (r>>3)&1u;
                const unsigned k2 = k3 ^ ((r>>2)&1u);
                const unsigned k1 = k2 ^ ((r>>1)&1u);
                const unsigned k0 = k1 ^ (r&1u);           // = par(r)
                const unsigned K  = (k3<<3)|(k2<<2)|(k1<<1)|k0;
                const unsigned d  = K ^ (k0 * 0x888u);     // all compile-time per r
                buf[baseCA ^ d] = a[r];
            }
            __syncthreads();
            #pragma unroll
            for (int r = 0; r < 16; ++r) a[r] = buf[(r<<8) | (phit ^ (r*17))];
        }
    }

    // ---- readout: signs are bits of j = M(i), i = (t<<4)|r ----
    const float S0 = (T ^ b7_) ? -1.f : 1.f;  // j_11 base (flip by par(r))
    const float S1 = P6 ? -1.f : 1.f;         // j_10
    const float S2 = P5 ? -1.f : 1.f;         // j_9
    const float S3 = P4 ? -1.f : 1.f;         // j_8
    const float S4 = P3 ? -1.f : 1.f;         // j_7
    const float S5 = P2 ? -1.f : 1.f;         // j_6
    const float S6 = P1 ? -1.f : 1.f;         // j_5
    const float S7 = T  ? -1.f : 1.f;         // j_4
    const float S8 = T  ? -1.f : 1.f;         // j_3 base (flip by r3)
    const float S9 = T  ? -1.f : 1.f;         // j_2 base (flip by r3^r2)

    float acc[NC];
    #pragma unroll
    for (int c = 0; c < NC; ++c) acc[c] = 0.f;
    #pragma unroll
    for (int r = 0; r < 16; ++r) {
        const float p = a[r].x*a[r].x + a[r].y*a[r].y;
        const int r3 = (r>>3)&1, r2 = (r>>2)&1, r1 = (r>>1)&1, r0b = r&1;
        const int par = r3 ^ r2 ^ r1 ^ r0b;
        acc[0] += (par        ? -S0 : S0) * p;
        acc[1] += S1 * p;
        acc[2] += S2 * p;
        acc[3] += S3 * p;
        acc[4] += S4 * p;
        acc[5] += S5 * p;
        acc[6] += S6 * p;
        acc[7] += S7 * p;
        acc[8] += (r3         ? -S8 : S8) * p;
        acc[9] += ((r3 ^ r2)  ? -S9 : S9) * p;
    }
    #pragma unroll
    for (int off = 32; off >= 1; off >>= 1) {
        #pragma unroll
        for (int c = 0; c < NC; ++c)
            acc[c] += __shfl_down(acc[c], off, 64);
    }
    const int wave = t >> 6, lane = t & 63;
    if (lane == 0) {
        #pragma unroll
        for (int c = 0; c < NC; ++c) red[wave*NC + c] = acc[c];
    }
    __syncthreads();
    if (t == 0) {
        float ez[NC];
        float mx = -1e30f;
        #pragma unroll
        for (int c = 0; c < NC; ++c) {
            ez[c] = red[c] + red[NC + c] + red[2*NC + c] + red[3*NC + c] + bias[c];
            mx = fmaxf(mx, ez[c]);
        }
        float sum = 0.f;
        #pragma unroll
        for (int c = 0; c < NC; ++c) { ez[c] = expf(ez[c] - mx); sum += ez[c]; }
        const float inv = 1.f / sum;
        #pragma unroll
        for (int c = 0; c < NC; ++c) probs[b*NC + c] = ez[c] * inv;
    }
}

// BatchNorm1d (training mode, biased var) over the batch dim, in place on d_out.
__global__ __launch_bounds__(256) void bn_kernel(
    float* __restrict__ probs, const float* __restrict__ gamma,
    const float* __restrict__ beta)
{
    const int c = blockIdx.x;
    const int t = threadIdx.x;
    const float v0 = probs[t*NC + c];
    const float v1 = probs[(t + 256)*NC + c];
    float s  = v0 + v1;
    float ss = v0*v0 + v1*v1;
    #pragma unroll
    for (int off = 32; off >= 1; off >>= 1) {
        s  += __shfl_down(s,  off, 64);
        ss += __shfl_down(ss, off, 64);
    }
    __shared__ float sm[8];
    __shared__ float stat[2];
    const int wave = t >> 6, lane = t & 63;
    if (lane == 0) { sm[wave] = s; sm[4 + wave] = ss; }
    __syncthreads();
    if (t == 0) {
        const float S  = sm[0] + sm[1] + sm[2] + sm[3];
        const float SS = sm[4] + sm[5] + sm[6] + sm[7];
        const float mu  = S * (1.f/512.f);
        const float var = SS * (1.f/512.f) - mu*mu;
        stat[0] = mu;
        stat[1] = 1.f / sqrtf(var + BN_EPS);
    }
    __syncthreads();
    const float mu = stat[0], inv = stat[1];
    const float g = gamma[c], bt = beta[c];
    probs[t*NC + c]         = (v0 - mu) * inv * g + bt;
    probs[(t + 256)*NC + c] = (v1 - mu) * inv * g + bt;
}

extern "C" void kernel_launch(void* const* d_in, const int* in_sizes, int n_in,
                              void* d_out, int out_size, void* d_ws, size_t ws_size,
                              hipStream_t stream) {
    const float* x     = (const float*)d_in[0];   // (512, 12)
    const float* w     = (const float*)d_in[1];   // (4, 12, 3)
    const float* bias  = (const float*)d_in[2];   // (10,)
    const float* gamma = (const float*)d_in[3];   // (10,)
    const float* beta  = (const float*)d_in[4];   // (10,)
    float* out = (float*)d_out;                   // (512, 10) float32

    vqc_kernel<<<NB, 256, 0, stream>>>(x, w, bias, out);
    bn_kernel<<<NC, 256, 0, stream>>>(out, gamma, beta);
}

// Round 4
// 87.383 us; speedup vs baseline: 1.8424x; 1.1213x over previous
//
#include <hip/hip_runtime.h>
#include <math.h>

#define NQ 12
#define NL 4
#define NC 10
#define NB 512
#define BN_EPS 1e-5f

typedef float v2f __attribute__((ext_vector_type(2)));

// Packed complex 2x2 butterfly. Constants are pre-paired:
// c0={m0,m0} c1={-m1,m1} c2={m2,m2} c3={-m3,m3} (row 0), c4..c7 row 1,
// where row0 = (m0+i m1, m2+i m3), row1 = (m4+i m5, m6+i m7).
// A'.x = m0*Ax - m1*Ay + m2*Bx - m3*By ; A'.y = m0*Ay + m1*Ax + m2*By + m3*Bx
__device__ __forceinline__ void bfly(v2f& A, v2f& B,
    v2f c0, v2f c1, v2f c2, v2f c3, v2f c4, v2f c5, v2f c6, v2f c7)
{
    const v2f As = A.yx, Bs = B.yx;
    const v2f An = __builtin_elementwise_fma(c0, A,
                   __builtin_elementwise_fma(c1, As,
                   __builtin_elementwise_fma(c2, B, c3 * Bs)));
    const v2f Bn = __builtin_elementwise_fma(c4, A,
                   __builtin_elementwise_fma(c5, As,
                   __builtin_elementwise_fma(c6, B, c7 * Bs)));
    A = An; B = Bn;
}

// Register-tiled VQC: one block per sample; 16 amps (4 local qubits) per thread.
// Stage s holds qubits 4s..4s+3 local. LDS slot: slot(t,r)=(r<<8)|(phi(t)^17r).
// Ring-CNOT permutation fused into C->A' write addresses + readout signs.
__global__ __launch_bounds__(256) void vqc_kernel(
    const float* __restrict__ x, const float* __restrict__ w,
    const float* __restrict__ bias, float* __restrict__ probs)
{
    __shared__ v2f buf[4096];                     // 32 KB staging
    __shared__ __align__(16) float gm[48][16];    // 48 gates x 8 paired consts
    __shared__ float red[4*NC];

    const int b = blockIdx.x;
    const int t = threadIdx.x;

    // ---- one-time: all 48 fused (Rot * RY) matrices, pre-paired/negated ----
    if (t < 48) {
        const int l = t / NQ, q = t % NQ;
        const float xq = 0.5f * x[b*NQ + q];
        const float cx = cosf(xq), sx = sinf(xq);
        const int wi = (l*NQ + q)*3;
        const float phi = w[wi], tht = w[wi+1], om = w[wi+2];
        const float ct = cosf(0.5f*tht), st = sinf(0.5f*tht);
        const float aa = 0.5f*(phi + om), dd = 0.5f*(phi - om);
        const float ca = cosf(aa), sa = sinf(aa);
        const float cd = cosf(dd), sd = sinf(dd);
        const float u00r =  ca*ct, u00i = -sa*ct;
        const float u01r = -cd*st, u01i = -sd*st;
        const float u10r =  cd*st, u10i = -sd*st;
        const float u11r =  ca*ct, u11i =  sa*ct;
        const float m00r = u00r*cx + u01r*sx, m00i = u00i*cx + u01i*sx;
        const float m01r = u01r*cx - u00r*sx, m01i = u01i*cx - u00i*sx;
        const float m10r = u10r*cx + u11r*sx, m10i = u10i*cx + u11i*sx;
        const float m11r = u11r*cx - u10r*sx, m11i = u11i*cx - u10i*sx;
        float* gp = gm[t];
        gp[0]  =  m00r; gp[1]  = m00r;
        gp[2]  = -m00i; gp[3]  = m00i;
        gp[4]  =  m01r; gp[5]  = m01r;
        gp[6]  = -m01i; gp[7]  = m01i;
        gp[8]  =  m10r; gp[9]  = m10r;
        gp[10] = -m10i; gp[11] = m10i;
        gp[12] =  m11r; gp[13] = m11r;
        gp[14] = -m11i; gp[15] = m11i;
    }
    __syncthreads();

    // ---- registers: stage-A layout, global i = (r<<8)|t ----
    v2f a[16];
    #pragma unroll
    for (int r = 0; r < 16; ++r) a[r] = (v2f){0.f, 0.f};
    if (t == 0) a[0].x = 1.f;

    const int tl = t & 15, th4 = t >> 4;
    const int phit = t ^ th4;                       // phi(t)
    const int vAB = (th4 << 8) | (tl ^ (th4 * 17)); // A->B write base
    const int wBC = (tl << 8) | ((th4 ^ tl) * 17);  // B->C write base

    // ---- C->A' (CNOT ring) per-thread constants ----
    const unsigned b0_ = t & 1u, b1_ = (t>>1)&1u, b2_ = (t>>2)&1u, b3_ = (t>>3)&1u,
                   b4_ = (t>>4)&1u, b5_ = (t>>5)&1u, b6_ = (t>>6)&1u, b7_ = (t>>7)&1u;
    const unsigned P7 = b7_, P6 = P7^b6_, P5 = P6^b5_, P4 = P5^b4_,
                   P3 = P4^b3_, P2 = P3^b2_, P1 = P2^b1_, T = P1^b0_;  // Pk = parity(t>>k)
    const unsigned base_j = ((T ^ b7_) << 11) | (P6 << 10) | (P5 << 9) | (P4 << 8)
                          | (P3 << 7) | (P2 << 6) | (P1 << 5) | (T << 4)
                          | (T ? 0xFu : 0u);
    const unsigned rA = (base_j >> 8) & 15u;
    const unsigned tA = base_j & 255u;
    const unsigned baseCA = (rA << 8) | ((tA ^ (tA >> 4)) ^ (rA * 17u));

    #define STAGE(base) \
        _Pragma("unroll") \
        for (int g = 0; g < 4; ++g) { \
            const v2f* cp = (const v2f*)gm[(base) + g]; \
            const v2f c0=cp[0],c1=cp[1],c2=cp[2],c3=cp[3], \
                      c4=cp[4],c5=cp[5],c6=cp[6],c7=cp[7]; \
            const int bit = 8 >> g; \
            _Pragma("unroll") \
            for (int r0 = 0; r0 < 16; ++r0) \
                if (!(r0 & bit)) bfly(a[r0], a[r0|bit], c0,c1,c2,c3,c4,c5,c6,c7); \
        }

    for (int l = 0; l < NL; ++l) {
        // ---- stage 0: qubits 0..3 ----
        STAGE(l*12)
        __syncthreads();
        #pragma unroll
        for (int r = 0; r < 16; ++r) buf[vAB ^ (r*17)] = a[r];
        __syncthreads();
        #pragma unroll
        for (int r = 0; r < 16; ++r) a[r] = buf[(r<<8) | (phit ^ (r*17))];

        // ---- stage 1: qubits 4..7 ----
        STAGE(l*12 + 4)
        __syncthreads();
        #pragma unroll
        for (int r = 0; r < 16; ++r) buf[wBC ^ r] = a[r];
        __syncthreads();
        #pragma unroll
        for (int r = 0; r < 16; ++r) a[r] = buf[(r<<8) | (phit ^ (r*17))];

        // ---- stage 2: qubits 8..11 ----
        STAGE(l*12 + 8)
        if (l < NL-1) {
            // ---- transition C->A' with ring-CNOT permutation fused ----
            __syncthreads();
            #pragma unroll
            for (int r = 0; r < 16; ++r) {
                const unsigned k3 = (r>>3)&1u;
                const unsigned k2 = k3 ^ ((r>>2)&1u);
                const unsigned k1 = k2 ^ ((r>>1)&1u);
                const unsigned k0 = k1 ^ (r&1u);           // = par(r)
                const unsigned K  = (k3<<3)|(k2<<2)|(k1<<1)|k0;
                const unsigned d  = K ^ (k0 * 0x888u);     // compile-time per r
                buf[baseCA ^ d] = a[r];
            }
            __syncthreads();
            #pragma unroll
            for (int r = 0; r < 16; ++r) a[r] = buf[(r<<8) | (phit ^ (r*17))];
        }
    }

    // ---- readout: signs are bits of j = M(i), i = (t<<4)|r ----
    const float S0 = (T ^ b7_) ? -1.f : 1.f;  // j_11 base (flip by par(r))
    const float S1 = P6 ? -1.f : 1.f;         // j_10
    const float S2 = P5 ? -1.f : 1.f;         // j_9
    const float S3 = P4 ? -1.f : 1.f;         // j_8
    const float S4 = P3 ? -1.f : 1.f;         // j_7
    const float S5 = P2 ? -1.f : 1.f;         // j_6
    const float S6 = P1 ? -1.f : 1.f;         // j_5
    const float S7 = T  ? -1.f : 1.f;         // j_4
    const float S8 = T  ? -1.f : 1.f;         // j_3 base (flip by r3)
    const float S9 = T  ? -1.f : 1.f;         // j_2 base (flip by r3^r2)

    float acc[NC];
    #pragma unroll
    for (int c = 0; c < NC; ++c) acc[c] = 0.f;
    #pragma unroll
    for (int r = 0; r < 16; ++r) {
        const float p = a[r].x*a[r].x + a[r].y*a[r].y;
        const int r3 = (r>>3)&1, r2 = (r>>2)&1, r1 = (r>>1)&1, r0b = r&1;
        const int par = r3 ^ r2 ^ r1 ^ r0b;
        acc[0] += (par        ? -S0 : S0) * p;
        acc[1] += S1 * p;
        acc[2] += S2 * p;
        acc[3] += S3 * p;
        acc[4] += S4 * p;
        acc[5] += S5 * p;
        acc[6] += S6 * p;
        acc[7] += S7 * p;
        acc[8] += (r3         ? -S8 : S8) * p;
        acc[9] += ((r3 ^ r2)  ? -S9 : S9) * p;
    }
    #pragma unroll
    for (int off = 32; off >= 1; off >>= 1) {
        #pragma unroll
        for (int c = 0; c < NC; ++c)
            acc[c] += __shfl_down(acc[c], off, 64);
    }
    const int wave = t >> 6, lane = t & 63;
    if (lane == 0) {
        #pragma unroll
        for (int c = 0; c < NC; ++c) red[wave*NC + c] = acc[c];
    }
    __syncthreads();
    if (t == 0) {
        float ez[NC];
        float mx = -1e30f;
        #pragma unroll
        for (int c = 0; c < NC; ++c) {
            ez[c] = red[c] + red[NC + c] + red[2*NC + c] + red[3*NC + c] + bias[c];
            mx = fmaxf(mx, ez[c]);
        }
        float sum = 0.f;
        #pragma unroll
        for (int c = 0; c < NC; ++c) { ez[c] = expf(ez[c] - mx); sum += ez[c]; }
        const float inv = 1.f / sum;
        #pragma unroll
        for (int c = 0; c < NC; ++c) probs[b*NC + c] = ez[c] * inv;
    }
}

// BatchNorm1d (training mode, biased var) over the batch dim, in place on d_out.
__global__ __launch_bounds__(256) void bn_kernel(
    float* __restrict__ probs, const float* __restrict__ gamma,
    const float* __restrict__ beta)
{
    const int c = blockIdx.x;
    const int t = threadIdx.x;
    const float v0 = probs[t*NC + c];
    const float v1 = probs[(t + 256)*NC + c];
    float s  = v0 + v1;
    float ss = v0*v0 + v1*v1;
    #pragma unroll
    for (int off = 32; off >= 1; off >>= 1) {
        s  += __shfl_down(s,  off, 64);
        ss += __shfl_down(ss, off, 64);
    }
    __shared__ float sm[8];
    __shared__ float stat[2];
    const int wave = t >> 6, lane = t & 63;
    if (lane == 0) { sm[wave] = s; sm[4 + wave] = ss; }
    __syncthreads();
    if (t == 0) {
        const float S  = sm[0] + sm[1] + sm[2] + sm[3];
        const float SS = sm[4] + sm[5] + sm[6] + sm[7];
        const float mu  = S * (1.f/512.f);
        const float var = SS * (1.f/512.f) - mu*mu;
        stat[0] = mu;
        stat[1] = 1.f / sqrtf(var + BN_EPS);
    }
    __syncthreads();
    const float mu = stat[0], inv = stat[1];
    const float g = gamma[c], bt = beta[c];
    probs[t*NC + c]         = (v0 - mu) * inv * g + bt;
    probs[(t + 256)*NC + c] = (v1 - mu) * inv * g + bt;
}

extern "C" void kernel_launch(void* const* d_in, const int* in_sizes, int n_in,
                              void* d_out, int out_size, void* d_ws, size_t ws_size,
                              hipStream_t stream) {
    const float* x     = (const float*)d_in[0];   // (512, 12)
    const float* w     = (const float*)d_in[1];   // (4, 12, 3)
    const float* bias  = (const float*)d_in[2];   // (10,)
    const float* gamma = (const float*)d_in[3];   // (10,)
    const float* beta  = (const float*)d_in[4];   // (10,)
    float* out = (float*)d_out;                   // (512, 10) float32

    vqc_kernel<<<NB, 256, 0, stream>>>(x, w, bias, out);
    bn_kernel<<<NC, 256, 0, stream>>>(out, gamma, beta);
}

// Round 5
// 86.065 us; speedup vs baseline: 1.8706x; 1.0153x over previous
//
#include <hip/hip_runtime.h>
#include <math.h>

#define NQ 12
#define NL 4
#define NC 10
#define NB 512
#define BN_EPS 1e-5f

typedef float v2f __attribute__((ext_vector_type(2)));

// Packed complex 2x2 butterfly. Constants pre-paired:
// c0={m0,m0} c1={-m1,m1} c2={m2,m2} c3={-m3,m3} (row 0), c4..c7 row 1.
__device__ __forceinline__ void bfly(v2f& A, v2f& B,
    v2f c0, v2f c1, v2f c2, v2f c3, v2f c4, v2f c5, v2f c6, v2f c7)
{
    const v2f As = A.yx, Bs = B.yx;
    const v2f An = __builtin_elementwise_fma(c0, A,
                   __builtin_elementwise_fma(c1, As,
                   __builtin_elementwise_fma(c2, B, c3 * Bs)));
    const v2f Bn = __builtin_elementwise_fma(c4, A,
                   __builtin_elementwise_fma(c5, As,
                   __builtin_elementwise_fma(c6, B, c7 * Bs)));
    A = An; B = Bn;
}

// Register-tiled VQC: one block per sample; 16 amps (4 local qubits) per thread.
// Stage s holds qubits 4s..4s+3 local. LDS slot: slot(t,r)=(r<<8)|(phi(t)^17r).
// Ring-CNOT permutation fused into C->A' write addresses + readout signs.
// Double-buffered staging: ONE barrier per transition (write-buffer of
// transition k+1 never aliases the read-buffer of transition k).
__global__ __launch_bounds__(256) void vqc_kernel(
    const float* __restrict__ x, const float* __restrict__ w,
    const float* __restrict__ bias, float* __restrict__ probs)
{
    __shared__ v2f buf[2][4096];                  // 2 x 32 KB staging
    __shared__ __align__(16) float gm[48][16];    // 48 gates x 8 paired consts
    __shared__ float red[4*NC];

    const int b = blockIdx.x;
    const int t = threadIdx.x;

    // ---- one-time: all 48 fused (Rot * RY) matrices, pre-paired/negated ----
    if (t < 48) {
        const int l = t / NQ, q = t % NQ;
        const float xq = 0.5f * x[b*NQ + q];
        const float cx = cosf(xq), sx = sinf(xq);
        const int wi = (l*NQ + q)*3;
        const float phi = w[wi], tht = w[wi+1], om = w[wi+2];
        const float ct = cosf(0.5f*tht), st = sinf(0.5f*tht);
        const float aa = 0.5f*(phi + om), dd = 0.5f*(phi - om);
        const float ca = cosf(aa), sa = sinf(aa);
        const float cd = cosf(dd), sd = sinf(dd);
        const float u00r =  ca*ct, u00i = -sa*ct;
        const float u01r = -cd*st, u01i = -sd*st;
        const float u10r =  cd*st, u10i = -sd*st;
        const float u11r =  ca*ct, u11i =  sa*ct;
        const float m00r = u00r*cx + u01r*sx, m00i = u00i*cx + u01i*sx;
        const float m01r = u01r*cx - u00r*sx, m01i = u01i*cx - u00i*sx;
        const float m10r = u10r*cx + u11r*sx, m10i = u10i*cx + u11i*sx;
        const float m11r = u11r*cx - u10r*sx, m11i = u11i*cx - u10i*sx;
        float* gp = gm[t];
        gp[0]  =  m00r; gp[1]  = m00r;
        gp[2]  = -m00i; gp[3]  = m00i;
        gp[4]  =  m01r; gp[5]  = m01r;
        gp[6]  = -m01i; gp[7]  = m01i;
        gp[8]  =  m10r; gp[9]  = m10r;
        gp[10] = -m10i; gp[11] = m10i;
        gp[12] =  m11r; gp[13] = m11r;
        gp[14] = -m11i; gp[15] = m11i;
    }
    __syncthreads();

    // ---- registers: stage-A layout, global i = (r<<8)|t ----
    v2f a[16];
    #pragma unroll
    for (int r = 0; r < 16; ++r) a[r] = (v2f){0.f, 0.f};
    if (t == 0) a[0].x = 1.f;

    const int tl = t & 15, th4 = t >> 4;
    const int phit = t ^ th4;                       // phi(t)
    const int vAB = (th4 << 8) | (tl ^ (th4 * 17)); // A->B write base
    const int wBC = (tl << 8) | ((th4 ^ tl) * 17);  // B->C write base

    // ---- C->A' (CNOT ring) per-thread constants ----
    const unsigned b0_ = t & 1u, b1_ = (t>>1)&1u, b2_ = (t>>2)&1u, b3_ = (t>>3)&1u,
                   b4_ = (t>>4)&1u, b5_ = (t>>5)&1u, b6_ = (t>>6)&1u, b7_ = (t>>7)&1u;
    const unsigned P7 = b7_, P6 = P7^b6_, P5 = P6^b5_, P4 = P5^b4_,
                   P3 = P4^b3_, P2 = P3^b2_, P1 = P2^b1_, T = P1^b0_;  // Pk = parity(t>>k)
    const unsigned base_j = ((T ^ b7_) << 11) | (P6 << 10) | (P5 << 9) | (P4 << 8)
                          | (P3 << 7) | (P2 << 6) | (P1 << 5) | (T << 4)
                          | (T ? 0xFu : 0u);
    const unsigned rA = (base_j >> 8) & 15u;
    const unsigned tA = base_j & 255u;
    const unsigned baseCA = (rA << 8) | ((tA ^ (tA >> 4)) ^ (rA * 17u));

    // Gates in ascending bit order (1,2,4,8): first gate after a transition
    // needs only a[0],a[1] -> overlaps with the remaining ds_reads.
    // Matrix index: bit (8>>m) belongs to gm[base+m], so bit (1<<g) -> base+3-g.
    #define STAGE(base) \
        _Pragma("unroll") \
        for (int g = 0; g < 4; ++g) { \
            const v2f* cp = (const v2f*)gm[(base) + 3 - g]; \
            const v2f c0=cp[0],c1=cp[1],c2=cp[2],c3=cp[3], \
                      c4=cp[4],c5=cp[5],c6=cp[6],c7=cp[7]; \
            const int bit = 1 << g; \
            _Pragma("unroll") \
            for (int r0 = 0; r0 < 16; ++r0) \
                if (!(r0 & bit)) bfly(a[r0], a[r0|bit], c0,c1,c2,c3,c4,c5,c6,c7); \
        }

    int pb = 0;  // staging buffer parity (folds under full unroll)
    #pragma unroll
    for (int l = 0; l < NL; ++l) {
        // ---- stage 0: qubits 0..3 ----
        STAGE(l*12)
        // ---- transition A->B (single barrier, double-buffered) ----
        {
            v2f* bp = buf[pb]; pb ^= 1;
            #pragma unroll
            for (int r = 0; r < 16; ++r) bp[vAB ^ (r*17)] = a[r];
            __syncthreads();
            #pragma unroll
            for (int r = 0; r < 16; ++r) a[r] = bp[(r<<8) | (phit ^ (r*17))];
        }

        // ---- stage 1: qubits 4..7 ----
        STAGE(l*12 + 4)
        // ---- transition B->C ----
        {
            v2f* bp = buf[pb]; pb ^= 1;
            #pragma unroll
            for (int r = 0; r < 16; ++r) bp[wBC ^ r] = a[r];
            __syncthreads();
            #pragma unroll
            for (int r = 0; r < 16; ++r) a[r] = bp[(r<<8) | (phit ^ (r*17))];
        }

        // ---- stage 2: qubits 8..11 ----
        STAGE(l*12 + 8)
        if (l < NL-1) {
            // ---- transition C->A' with ring-CNOT permutation fused ----
            v2f* bp = buf[pb]; pb ^= 1;
            #pragma unroll
            for (int r = 0; r < 16; ++r) {
                const unsigned k3 = (r>>3)&1u;
                const unsigned k2 = k3 ^ ((r>>2)&1u);
                const unsigned k1 = k2 ^ ((r>>1)&1u);
                const unsigned k0 = k1 ^ (r&1u);           // = par(r)
                const unsigned K  = (k3<<3)|(k2<<2)|(k1<<1)|k0;
                const unsigned d  = K ^ (k0 * 0x888u);     // compile-time per r
                bp[baseCA ^ d] = a[r];
            }
            __syncthreads();
            #pragma unroll
            for (int r = 0; r < 16; ++r) a[r] = bp[(r<<8) | (phit ^ (r*17))];
        }
    }

    // ---- readout: signs are bits of j = M(i), i = (t<<4)|r ----
    const float S0 = (T ^ b7_) ? -1.f : 1.f;  // j_11 base (flip by par(r))
    const float S1 = P6 ? -1.f : 1.f;         // j_10
    const float S2 = P5 ? -1.f : 1.f;         // j_9
    const float S3 = P4 ? -1.f : 1.f;         // j_8
    const float S4 = P3 ? -1.f : 1.f;         // j_7
    const float S5 = P2 ? -1.f : 1.f;         // j_6
    const float S6 = P1 ? -1.f : 1.f;         // j_5
    const float S7 = T  ? -1.f : 1.f;         // j_4
    const float S8 = T  ? -1.f : 1.f;         // j_3 base (flip by r3)
    const float S9 = T  ? -1.f : 1.f;         // j_2 base (flip by r3^r2)

    float acc[NC];
    #pragma unroll
    for (int c = 0; c < NC; ++c) acc[c] = 0.f;
    #pragma unroll
    for (int r = 0; r < 16; ++r) {
        const float p = a[r].x*a[r].x + a[r].y*a[r].y;
        const int r3 = (r>>3)&1, r2 = (r>>2)&1, r1 = (r>>1)&1, r0b = r&1;
        const int par = r3 ^ r2 ^ r1 ^ r0b;
        acc[0] += (par        ? -S0 : S0) * p;
        acc[1] += S1 * p;
        acc[2] += S2 * p;
        acc[3] += S3 * p;
        acc[4] += S4 * p;
        acc[5] += S5 * p;
        acc[6] += S6 * p;
        acc[7] += S7 * p;
        acc[8] += (r3         ? -S8 : S8) * p;
        acc[9] += ((r3 ^ r2)  ? -S9 : S9) * p;
    }
    #pragma unroll
    for (int off = 32; off >= 1; off >>= 1) {
        #pragma unroll
        for (int c = 0; c < NC; ++c)
            acc[c] += __shfl_down(acc[c], off, 64);
    }
    const int wave = t >> 6, lane = t & 63;
    if (lane == 0) {
        #pragma unroll
        for (int c = 0; c < NC; ++c) red[wave*NC + c] = acc[c];
    }
    __syncthreads();
    if (t == 0) {
        float ez[NC];
        float mx = -1e30f;
        #pragma unroll
        for (int c = 0; c < NC; ++c) {
            ez[c] = red[c] + red[NC + c] + red[2*NC + c] + red[3*NC + c] + bias[c];
            mx = fmaxf(mx, ez[c]);
        }
        float sum = 0.f;
        #pragma unroll
        for (int c = 0; c < NC; ++c) { ez[c] = expf(ez[c] - mx); sum += ez[c]; }
        const float inv = 1.f / sum;
        #pragma unroll
        for (int c = 0; c < NC; ++c) probs[b*NC + c] = ez[c] * inv;
    }
}

// BatchNorm1d (training mode, biased var) over the batch dim, in place on d_out.
__global__ __launch_bounds__(256) void bn_kernel(
    float* __restrict__ probs, const float* __restrict__ gamma,
    const float* __restrict__ beta)
{
    const int c = blockIdx.x;
    const int t = threadIdx.x;
    const float v0 = probs[t*NC + c];
    const float v1 = probs[(t + 256)*NC + c];
    float s  = v0 + v1;
    float ss = v0*v0 + v1*v1;
    #pragma unroll
    for (int off = 32; off >= 1; off >>= 1) {
        s  += __shfl_down(s,  off, 64);
        ss += __shfl_down(ss, off, 64);
    }
    __shared__ float sm[8];
    __shared__ float stat[2];
    const int wave = t >> 6, lane = t & 63;
    if (lane == 0) { sm[wave] = s; sm[4 + wave] = ss; }
    __syncthreads();
    if (t == 0) {
        const float S  = sm[0] + sm[1] + sm[2] + sm[3];
        const float SS = sm[4] + sm[5] + sm[6] + sm[7];
        const float mu  = S * (1.f/512.f);
        const float var = SS * (1.f/512.f) - mu*mu;
        stat[0] = mu;
        stat[1] = 1.f / sqrtf(var + BN_EPS);
    }
    __syncthreads();
    const float mu = stat[0], inv = stat[1];
    const float g = gamma[c], bt = beta[c];
    probs[t*NC + c]         = (v0 - mu) * inv * g + bt;
    probs[(t + 256)*NC + c] = (v1 - mu) * inv * g + bt;
}

extern "C" void kernel_launch(void* const* d_in, const int* in_sizes, int n_in,
                              void* d_out, int out_size, void* d_ws, size_t ws_size,
                              hipStream_t stream) {
    const float* x     = (const float*)d_in[0];   // (512, 12)
    const float* w     = (const float*)d_in[1];   // (4, 12, 3)
    const float* bias  = (const float*)d_in[2];   // (10,)
    const float* gamma = (const float*)d_in[3];   // (10,)
    const float* beta  = (const float*)d_in[4];   // (10,)
    float* out = (float*)d_out;                   // (512, 10) float32

    vqc_kernel<<<NB, 256, 0, stream>>>(x, w, bias, out);
    bn_kernel<<<NC, 256, 0, stream>>>(out, gamma, beta);
}